// Round 1
// baseline (72.925 us; speedup 1.0000x reference)
//
#include <hip/hip_runtime.h>
#include <math.h>

// QuantumLSTMClassifier — analytic collapse.
//
// Key identity: H|0> = |+> is an X eigenstate, so RX(q_in) only adds a global
// phase; CNOTs permute the computational basis; PauliZ expectations of the
// product state factorize. Hence q_feat depends only on qw:
//   z_j       = -sin(qw[g,0,j])
//   feat[g,0] = prod_{j=1..7} z_j          (Z_0 -> Z_1...Z_7 under CNOT ring)
//   feat[g,w] = prod_{j=0..w} z_j  (w>=1)  (Z_w -> Z_0...Z_w)
// => gates, f/i/g/o, and the whole h_t sequence are input-independent.
// Output depends on x only via the padding mask:
//   out[b,c] = (sum_{t: x[b,t]!=0} s_t[c]) / (cnt_b + 1e-9) + fcb[c]
//   s_t[c]   = sum_h fcW[c,h] * h_t[h]

__device__ __forceinline__ float sigmoidf_(float v) { return 1.0f / (1.0f + expf(-v)); }

// One block per timestep t (128 blocks), one thread per hidden unit h (256).
__global__ __launch_bounds__(256) void qlstm_stab(
    const float* __restrict__ qw,    // (4,2,8)
    const float* __restrict__ Wo,    // (4,256,8)
    const float* __restrict__ bo,    // (4,256)
    const float* __restrict__ fcW,   // (2,256)
    float* __restrict__ s_tab)       // (128,2) in ws
{
  __shared__ float feat[4][8];
  __shared__ float red[8];
  const int t = blockIdx.x;
  const int h = threadIdx.x;

  if (h < 4) {
    const int g = h;
    float z[8];
#pragma unroll
    for (int j = 0; j < 8; ++j) z[j] = -sinf(qw[g * 16 + j]);  // qw[g][0][j]
    float p = z[1];
#pragma unroll
    for (int j = 2; j < 8; ++j) p *= z[j];
    feat[g][0] = p;                       // prod j=1..7
    p = z[0];
#pragma unroll
    for (int w = 1; w < 8; ++w) { p *= z[w]; feat[g][w] = p; }  // prod j=0..w
  }
  __syncthreads();

  float gate[4];
#pragma unroll
  for (int g = 0; g < 4; ++g) {
    const float* wrow = Wo + ((g << 8) + h) * 8;  // Wo[g][h][:]
    float acc = bo[(g << 8) + h];
#pragma unroll
    for (int q = 0; q < 8; ++q) acc += wrow[q] * feat[g][q];
    gate[g] = acc;
  }
  const float f  = sigmoidf_(gate[0]);
  const float ii = sigmoidf_(gate[1]);
  const float gg = tanhf(gate[2]);
  const float o  = sigmoidf_(gate[3]);
  const float S  = ii * gg;

  // Iterate the recurrence exactly as the reference does (t+1 updates).
  float c = 0.0f;
  for (int k = 0; k <= t; ++k) c = f * c + S;
  const float ht = o * tanhf(c);

  float p0 = fcW[h]       * ht;   // fcW[0][h]
  float p1 = fcW[256 + h] * ht;   // fcW[1][h]
#pragma unroll
  for (int off = 32; off > 0; off >>= 1) {
    p0 += __shfl_down(p0, off);
    p1 += __shfl_down(p1, off);
  }
  const int lane = h & 63, wv = h >> 6;
  if (lane == 0) { red[wv * 2] = p0; red[wv * 2 + 1] = p1; }
  __syncthreads();
  if (h == 0) {
    s_tab[t * 2 + 0] = red[0] + red[2] + red[4] + red[6];
    s_tab[t * 2 + 1] = red[1] + red[3] + red[5] + red[7];
  }
}

// One 64-lane wave per batch row; 4 rows per 256-thread block.
__global__ __launch_bounds__(256) void qlstm_pool(
    const int* __restrict__ x,       // (B,128) int32
    const float* __restrict__ s_tab, // (128,2)
    const float* __restrict__ fcb,   // (2,)
    float* __restrict__ out)         // (B,2)
{
  __shared__ float ss[256];
  const int tid = threadIdx.x;
  ss[tid] = s_tab[tid];
  __syncthreads();

  const int lane = tid & 63, wv = tid >> 6;
  const int b = (blockIdx.x << 2) + wv;
  const int* xb = x + b * 128;

  const int t0 = lane, t1 = lane + 64;
  const int m0 = (xb[t0] != 0) ? 1 : 0;   // coalesced: lanes read 64 consecutive ints
  const int m1 = (xb[t1] != 0) ? 1 : 0;
  float cnt = (float)(m0 + m1);
  float a0 = 0.0f, a1 = 0.0f;
  if (m0) { a0 += ss[t0 * 2]; a1 += ss[t0 * 2 + 1]; }
  if (m1) { a0 += ss[t1 * 2]; a1 += ss[t1 * 2 + 1]; }

#pragma unroll
  for (int off = 32; off > 0; off >>= 1) {
    cnt += __shfl_down(cnt, off);
    a0  += __shfl_down(a0, off);
    a1  += __shfl_down(a1, off);
  }
  if (lane == 0) {
    const float inv = 1.0f / (cnt + 1e-9f);
    out[b * 2 + 0] = a0 * inv + fcb[0];
    out[b * 2 + 1] = a1 * inv + fcb[1];
  }
}

extern "C" void kernel_launch(void* const* d_in, const int* in_sizes, int n_in,
                              void* d_out, int out_size, void* d_ws, size_t ws_size,
                              hipStream_t stream) {
  // setup_inputs order: x, embed, Wi, bi, qw, Wo, bo, fcW, fcb
  const int*   x    = (const int*)  d_in[0];
  const float* qw   = (const float*)d_in[4];
  const float* Wo   = (const float*)d_in[5];
  const float* bo   = (const float*)d_in[6];
  const float* fcW  = (const float*)d_in[7];
  const float* fcb  = (const float*)d_in[8];
  float* out = (float*)d_out;
  float* s_tab = (float*)d_ws;  // 128*2 floats

  const int T = 128;
  const int B = in_sizes[0] / T;  // 1024

  qlstm_stab<<<T, 256, 0, stream>>>(qw, Wo, bo, fcW, s_tab);
  qlstm_pool<<<B / 4, 256, 0, stream>>>(x, s_tab, fcb, out);
}